// Round 12
// baseline (461.354 us; speedup 1.0000x reference)
//
#include <hip/hip_runtime.h>
#include <stdint.h>

#define T_STEPS 2048
#define BB 64
#define CC 128
#define HH 256
#define NCLS 10

// ws layout:
//   s1  bytes [T][B][C]     : 2048*64*128 = 16777216 B  (0/1 spikes, i8 A-operand)
//   dp  i8   [4][H][C]      : 4*256*128   =   131072 B  (W1 digit planes)
//   dp2 i8   [4][16][256]   : 4*16*256    =    16384 B  (W2 digit planes, nc padded)
//   s2w dwords [T][B][8]    : 2048*64*32  =  4194304 B  (layer-2 spike BITS)
//   bar u32[2] (+pad)       : at 21118976 (separate 64B lines), memset to 0
//                             each call by a 256 B hipMemsetAsync.
#define S1_OFF  0
#define DP_OFF  16777216
#define DP2_OFF 16908288
#define S2W_OFF 16924672
#define BAR_OFF 21118976

typedef int v4i __attribute__((ext_vector_type(4)));

#define NBLK 1024u

// software grid barrier: all 1024 blocks are co-resident (4 blocks/CU via
// __launch_bounds__(256,4): VGPR<=128, 16 waves/CU, ~1 KB LDS). Release fence
// (agent scope -> buffer_wbl2: cross-XCD L2 writeback) + device-scope add +
// acquire spin. Same mechanism ROCm's grid.sync() uses, minus the coop API.
__device__ __forceinline__ void grid_barrier(unsigned* cnt) {
  __syncthreads();
  if (threadIdx.x == 0) {
    __threadfence();
    __hip_atomic_fetch_add(cnt, 1u, __ATOMIC_RELEASE, __HIP_MEMORY_SCOPE_AGENT);
    while (__hip_atomic_load(cnt, __ATOMIC_ACQUIRE, __HIP_MEMORY_SCOPE_AGENT) <
           NBLK) {
      __builtin_amdgcn_s_sleep(2);
    }
    __threadfence();
  }
  __syncthreads();
}

// ---------------- Fused kernel: prep | gemm2+LIF2 | gemm3+LIF3 ----------------
// P1: conv+LIF1 -> s1 (tid<128; chunk=bx>>6, b=bx&63; 128 t + 64 warmup, LDS-
//     staged x row) + digit planes / out-zero on tid>=128 of blocks 0..272.
// P2: R8-best K2 (51.6 us): (hg=bx>>9, b=(bx>>3)&63, chunk=bx&7), 256-t chunks
//     + 64 warmup; per 16-t sub: 16 x mfma_i32_16x16x64_i8, exact digit
//     recombine, bpermute transpose, in-lane 16-step LIF, ballot -> s2 bits.
// P3: R9 k34: wave-per-32t-chunk (b=bx&63, cg=(bx>>6)*4+wv), bit decode ->
//     MFMA -> recombine -> transpose -> in-lane LIF3 + count -> atomicAdd.
// All numeric paths byte-identical to the absmax-0 R8/R9 kernels.
__global__ __launch_bounds__(256, 4) void snn_fused(
    const float* __restrict__ x, const float* __restrict__ cw,
    const float* __restrict__ W1, const float* __restrict__ W2,
    unsigned char* __restrict__ s1, signed char* __restrict__ dp,
    signed char* __restrict__ dp2, unsigned int* __restrict__ s2w,
    unsigned* __restrict__ bar, float* __restrict__ out) {
  const int bx  = blockIdx.x;
  const int tid = threadIdx.x;

  // ================= P1: conv+LIF1 + digits + out-zero =================
  {
    __shared__ float xs[200];
    const int b  = bx & 63;
    const int t0 = (bx >> 6) * 128;
    const float* xb = x + b * 2048;
    if (tid < 128) {
      for (int i = tid; i < 200; i += 128) {
        int l = t0 - 67 + i;
        xs[i] = (l >= 0 && l < 2048) ? xb[l] : 0.0f;
      }
    }
    __syncthreads();

    if (tid < 128) {
      const int c  = tid;
      const int ts = t0 - 64;
      float w[7];
#pragma unroll
      for (int k = 0; k < 7; ++k) w[k] = cw[c * 7 + k];
      float xw[7];
#pragma unroll
      for (int k = 0; k < 7; ++k) xw[k] = xs[k];
      float v = 0.0f;
#pragma unroll 7
      for (int i = 0; i < 192; ++i) {            // t = ts + i
        float u = fmaf(w[0], xw[0],
                  fmaf(w[1], xw[1],
                  fmaf(w[2], xw[2],
                  fmaf(w[3], xw[3],
                  fmaf(w[4], xw[4],
                  fmaf(w[5], xw[5], w[6] * xw[6]))))));
        v = fmaf(v, 0.5f, u);        // v*0.5 exact -> fmaf == ref mul-then-add
        bool sp = (v >= 1.0f);
        if (i >= 64) {
          int t = ts + i;
          s1[((size_t)t * BB + b) * CC + c] = (unsigned char)(sp ? 1 : 0);
        }
        if (sp) v = 0.0f;
#pragma unroll
        for (int k = 0; k < 6; ++k) xw[k] = xw[k + 1];
        xw[6] = xs[i + 7];
      }
    } else if (bx < 256) {
      // W1 digits: q = rn(w*2^31) = d0 + 256*(d1 + 256*(d2 + 256*d3)), exact.
      const int h = bx, c = tid - 128;
      float w = W1[h * CC + c];
      int q = __float2int_rn(w * 2147483648.0f);
#pragma unroll
      for (int d = 0; d < 3; ++d) {
        int dig = (int)(signed char)(q & 0xff);
        dp[d * (HH * CC) + h * CC + c] = (signed char)dig;
        q = (q - dig) >> 8;
      }
      dp[3 * (HH * CC) + h * CC + c] = (signed char)q;
    } else if (bx < 272) {
      const int nc = bx - 256;
#pragma unroll
      for (int half = 0; half < 2; ++half) {
        int cc = half * 128 + (tid - 128);
        float w = (nc < NCLS) ? W2[nc * HH + cc] : 0.0f;
        int q = __float2int_rn(w * 2147483648.0f);
#pragma unroll
        for (int d = 0; d < 3; ++d) {
          int dig = (int)(signed char)(q & 0xff);
          dp2[d * (16 * HH) + nc * HH + cc] = (signed char)dig;
          q = (q - dig) >> 8;
        }
        dp2[3 * (16 * HH) + nc * HH + cc] = (signed char)q;
      }
    } else if (bx == 272) {
      const int i = tid - 128;
#pragma unroll
      for (int k = 0; k < 5; ++k) out[i + 128 * k] = 0.0f;   // 640 = 5*128
    }
  }

  grid_barrier(bar);

  // ================= P2: MFMA-i8 (s1 @ W1^T) + LIF2 -> s2 bits =================
  {
    const int lane = tid & 63;
    const int wv   = tid >> 6;
    const int hg   = bx >> 9;         // 0..1
    const int b    = (bx >> 3) & 63;  // 0..63
    const int chunk= bx & 7;          // 0..7
    const int t0   = chunk * 256;
    const int nwarm= (chunk == 0) ? 0 : 4;
    const int ts   = t0 - nwarm * 16;
    const int l15  = lane & 15;
    const int lg   = lane >> 4;
    const int nn   = lg >> 1;
    const int hb   = hg * 128 + wv * 32;

    v4i Bf[2][4][2];
#pragma unroll
    for (int n = 0; n < 2; ++n)
#pragma unroll
      for (int d = 0; d < 4; ++d)
#pragma unroll
        for (int kc = 0; kc < 2; ++kc)
          Bf[n][d][kc] = *(const v4i*)(dp + d * (HH * CC) +
                                       (hb + n * 16 + l15) * CC + kc * 64 + lg * 16);

    const unsigned char* ap =
        s1 + ((size_t)(ts + l15) * BB + b) * CC + lg * 16;
    v4i Af0 = *(const v4i*)(ap);
    v4i Af1 = *(const v4i*)(ap + 64);
    ap += 16 * BB * CC;

    const int a4 = l15 * 4;
    float v = 0.0f;

    const int nsub = nwarm + 16;
    for (int s = 0; s < nsub; ++s) {
      const int tb = ts + s * 16;

      v4i Pf0 = *(const v4i*)(ap);     // final overrun lands in dp region
      v4i Pf1 = *(const v4i*)(ap + 64);
      ap += 16 * BB * CC;

      float u0[4], u1[4];
#pragma unroll
      for (int n = 0; n < 2; ++n) {
        v4i a0 = {0, 0, 0, 0}, a1 = {0, 0, 0, 0}, a2 = {0, 0, 0, 0}, a3 = {0, 0, 0, 0};
        a0 = __builtin_amdgcn_mfma_i32_16x16x64_i8(Af0, Bf[n][0][0], a0, 0, 0, 0);
        a1 = __builtin_amdgcn_mfma_i32_16x16x64_i8(Af0, Bf[n][1][0], a1, 0, 0, 0);
        a2 = __builtin_amdgcn_mfma_i32_16x16x64_i8(Af0, Bf[n][2][0], a2, 0, 0, 0);
        a3 = __builtin_amdgcn_mfma_i32_16x16x64_i8(Af0, Bf[n][3][0], a3, 0, 0, 0);
        a0 = __builtin_amdgcn_mfma_i32_16x16x64_i8(Af1, Bf[n][0][1], a0, 0, 0, 0);
        a1 = __builtin_amdgcn_mfma_i32_16x16x64_i8(Af1, Bf[n][1][1], a1, 0, 0, 0);
        a2 = __builtin_amdgcn_mfma_i32_16x16x64_i8(Af1, Bf[n][2][1], a2, 0, 0, 0);
        a3 = __builtin_amdgcn_mfma_i32_16x16x64_i8(Af1, Bf[n][3][1], a3, 0, 0, 0);
#pragma unroll
        for (int r = 0; r < 4; ++r) {
          int hi = a3[r] * 256 + a2[r];           // exact, |.| < 2^24
          int lo = a1[r] * 256 + a0[r];
          float u = fmaf((float)hi, 0x1p-15f, (float)lo * 0x1p-31f);
          if (n == 0) u0[r] = u; else u1[r] = u;
        }
      }

      float ua[16];
#pragma unroll
      for (int q = 0; q < 4; ++q) {
        const int addr = a4 + q * 64;
#pragma unroll
        for (int r = 0; r < 4; ++r) {
          int g0 = __builtin_amdgcn_ds_bpermute(addr, __float_as_int(u0[r]));
          int g1 = __builtin_amdgcn_ds_bpermute(addr, __float_as_int(u1[r]));
          ua[q * 4 + r] = __int_as_float(nn ? g1 : g0);
        }
      }

      unsigned sel = 0;
#pragma unroll
      for (int j = 0; j < 16; ++j) {
        v = fmaf(v, 0.5f, ua[j]);
        bool sp = (v >= 1.0f);
        if (sp) v = 0.0f;
        unsigned long long Bm = __ballot(sp);
        if (l15 == j)
          sel = (unsigned)(Bm & 0xFFFFull) |
                ((unsigned)((Bm >> 32) & 0xFFFFull) << 16);
      }

      if (s >= nwarm && lg == 0)
        s2w[((size_t)(tb + l15) * BB + b) * 8 + hg * 4 + wv] = sel;

      Af0 = Pf0; Af1 = Pf1;
    }
  }

  grid_barrier(bar + 16);

  // ================= P3: MFMA-i8 (s2bits @ W2^T) + LIF3 + count =================
  {
    const int lane = tid & 63;
    const int wv   = tid >> 6;
    const int l15  = lane & 15;
    const int lg   = lane >> 4;
    const int b    = bx & 63;
    const int cg   = ((bx >> 6) << 2) | wv;   // 0..63, 32-t chunk per wave
    const int t0   = cg * 32;
    const int nwarm= (cg == 0) ? 0 : 4;
    const int ts   = t0 - nwarm * 16;

    v4i Bf[4][4];
#pragma unroll
    for (int d = 0; d < 4; ++d)
#pragma unroll
      for (int kc = 0; kc < 4; ++kc)
        Bf[d][kc] = *(const v4i*)(dp2 + d * (16 * HH) + l15 * HH + kc * 64 + lg * 16);

    const uint4* rp = (const uint4*)s2w + ((size_t)(ts + l15) * BB + b) * 2;
    uint4 r0 = rp[0], r1 = rp[1];
    rp += 16 * BB * 2;

    const int a4 = l15 * 4;
    const int hw = (lg & 1) * 16;
    float v = 0.0f, cnt = 0.0f;

    const int nsub = nwarm + 2;
    for (int s = 0; s < nsub; ++s) {
      uint4 p0 = rp[0], p1 = rp[1];   // overrun past s2w lands in ws slack
      rp += 16 * BB * 2;

      unsigned rowd[8] = {r0.x, r0.y, r0.z, r0.w, r1.x, r1.y, r1.z, r1.w};

      v4i a0 = {0, 0, 0, 0}, a1 = {0, 0, 0, 0}, a2 = {0, 0, 0, 0}, a3 = {0, 0, 0, 0};
#pragma unroll
      for (int kc = 0; kc < 4; ++kc) {
        unsigned h16 = (rowd[kc * 2 + (lg >> 1)] >> hw) & 0xFFFFu;
        v4i Af;
        Af[0] = (int)(((h16 & 0xFu) * 0x00204081u) & 0x01010101u);
        Af[1] = (int)((((h16 >> 4) & 0xFu) * 0x00204081u) & 0x01010101u);
        Af[2] = (int)((((h16 >> 8) & 0xFu) * 0x00204081u) & 0x01010101u);
        Af[3] = (int)((((h16 >> 12) & 0xFu) * 0x00204081u) & 0x01010101u);
        a0 = __builtin_amdgcn_mfma_i32_16x16x64_i8(Af, Bf[0][kc], a0, 0, 0, 0);
        a1 = __builtin_amdgcn_mfma_i32_16x16x64_i8(Af, Bf[1][kc], a1, 0, 0, 0);
        a2 = __builtin_amdgcn_mfma_i32_16x16x64_i8(Af, Bf[2][kc], a2, 0, 0, 0);
        a3 = __builtin_amdgcn_mfma_i32_16x16x64_i8(Af, Bf[3][kc], a3, 0, 0, 0);
      }

      float u[4];
#pragma unroll
      for (int r = 0; r < 4; ++r) {
        int hi = a3[r] * 256 + a2[r];
        int lo = a1[r] * 256 + a0[r];
        u[r] = fmaf((float)hi, 0x1p-15f, (float)lo * 0x1p-31f);
      }

      float ua[16];
#pragma unroll
      for (int q = 0; q < 4; ++q) {
        const int addr = a4 + q * 64;
#pragma unroll
        for (int r = 0; r < 4; ++r)
          ua[q * 4 + r] = __int_as_float(
              __builtin_amdgcn_ds_bpermute(addr, __float_as_int(u[r])));
      }

      float inc = (s >= nwarm) ? 1.0f : 0.0f;
#pragma unroll
      for (int j = 0; j < 16; ++j) {
        v = fmaf(v, 0.5f, ua[j]);
        bool sp = (v >= 1.0f);
        if (sp) { v = 0.0f; cnt += inc; }
      }

      r0 = p0; r1 = p1;
    }

    if (lane < NCLS)
      atomicAdd(&out[b * NCLS + lane], cnt * (1.0f / 2048.0f));  // exact dyadic
  }
}

extern "C" void kernel_launch(void* const* d_in, const int* in_sizes, int n_in,
                              void* d_out, int out_size, void* d_ws, size_t ws_size,
                              hipStream_t stream) {
  const float* x  = (const float*)d_in[0];   // [64,2048]
  const float* cw = (const float*)d_in[1];   // [128,1,7]
  const float* W1 = (const float*)d_in[2];   // [256,128]
  const float* W2 = (const float*)d_in[3];   // [10,256]
  float* out = (float*)d_out;                // [64,10]

  char* ws = (char*)d_ws;
  unsigned char* s1  = (unsigned char*)(ws + S1_OFF);
  signed char*   dp  = (signed char*)(ws + DP_OFF);
  signed char*   dp2 = (signed char*)(ws + DP2_OFF);
  unsigned int*  s2w = (unsigned int*)(ws + S2W_OFF);
  unsigned*      bar = (unsigned*)(ws + BAR_OFF);

  hipMemsetAsync(bar, 0, 256, stream);   // zero both barrier counters
  snn_fused<<<dim3(NBLK), 256, 0, stream>>>(x, cw, W1, W2, s1, dp, dp2, s2w,
                                            bar, out);
  (void)in_sizes; (void)n_in; (void)out_size; (void)ws_size;
}

// Round 13
// 270.624 us; speedup vs baseline: 1.7048x; 1.7048x over previous
//
#include <hip/hip_runtime.h>
#include <stdint.h>

#define T_STEPS 2048
#define BB 64
#define CC 128
#define HH 256
#define NCLS 10

// ws layout:
//   s1  bytes [T][B][C]   : 2048*64*128 = 16777216 B  (0/1 spikes, i8 A-operand)
//   s2w dwords [T][B][8]  : 2048*64*32  =  4194304 B  (layer-2 spike bits)
//   bar u32 counters      : at 22020096, cnt1[64] + cnt2[64], 64 B apart
//                           (zeroed each call by an 8 KB hipMemsetAsync)
#define S1_OFF  0
#define S2W_OFF 16777216
#define BAR_OFF 22020096

typedef int v4i __attribute__((ext_vector_type(4)));

// ---- exact signed base-256 digitization: 16 weights -> 4 digit-plane v4i ----
// q = rn(w*2^31); the unique digits d0..d3 in [-128,127] with
// q = d0+256*(d1+256*(d2+256*d3)) are the bytes of (q+0x80808080)^0x80808080
// (balanced radix-256; bit-identical to R8's borrow loop). 4x4 byte transpose
// via v_perm_b32 packs weight-major -> digit-major.
__device__ __forceinline__ void digitize16(const float* __restrict__ w,
                                           v4i out[4]) {
  int X[4][4];
#pragma unroll
  for (int g = 0; g < 4; ++g) {
    unsigned m[4];
#pragma unroll
    for (int j = 0; j < 4; ++j) {
      int q = __float2int_rn(w[4 * g + j] * 2147483648.0f);
      m[j] = ((unsigned)q + 0x80808080u) ^ 0x80808080u;
    }
    unsigned p01l = __builtin_amdgcn_perm(m[1], m[0], 0x05010400u);
    unsigned p01h = __builtin_amdgcn_perm(m[1], m[0], 0x07030602u);
    unsigned p23l = __builtin_amdgcn_perm(m[3], m[2], 0x05010400u);
    unsigned p23h = __builtin_amdgcn_perm(m[3], m[2], 0x07030602u);
    X[g][0] = (int)__builtin_amdgcn_perm(p23l, p01l, 0x05040100u);
    X[g][1] = (int)__builtin_amdgcn_perm(p23l, p01l, 0x07060302u);
    X[g][2] = (int)__builtin_amdgcn_perm(p23h, p01h, 0x05040100u);
    X[g][3] = (int)__builtin_amdgcn_perm(p23h, p01h, 0x07060302u);
  }
#pragma unroll
  for (int d = 0; d < 4; ++d) {
    v4i r;
#pragma unroll
    for (int g = 0; g < 4; ++g) r[g] = X[g][d];
    out[d] = r;
  }
}

// ---- distributed producer/consumer sync (per-b counters, 64 B lines) --------
// Release: syncthreads (all block's writes done) + fence + relaxed-RMW add
// (RMWs continue release sequences -> consumer reading 16 syncs with all 16).
// Acquire: RELAXED polls (no cache maintenance per poll!) + one fence after.
__device__ __forceinline__ void release_count(unsigned* cnt) {
  __syncthreads();
  if (threadIdx.x == 0) {
    __threadfence();
    __hip_atomic_fetch_add(cnt, 1u, __ATOMIC_RELEASE, __HIP_MEMORY_SCOPE_AGENT);
  }
}
__device__ __forceinline__ void acquire_count(unsigned* cnt, unsigned tgt) {
  if (threadIdx.x == 0) {
    while (__hip_atomic_load(cnt, __ATOMIC_RELAXED, __HIP_MEMORY_SCOPE_AGENT) <
           tgt)
      __builtin_amdgcn_s_sleep(8);
    __threadfence();
  }
  __syncthreads();
}

// ---------------- Fused kernel, per-b pipelined, 1024 blocks co-resident ------
// A: conv+LIF1 -> s1 (b=bx&63, tchunk=bx>>6; 128 t + 64 warmup, LDS-staged x);
//    blocks bx<64 also zero out[b]. release cnt1[b].
// B: (hg=bx>>9, b=(bx>>3)&63, chunk=bx&7): digitize own W1 slice in-register,
//    wait cnt1[b]==16, then R8's verbatim MFMA+LIF2+ballot loop. release cnt2[b].
// C: (b=bx&63, cg=(bx>>6)*4+wv): digitize own W2 slice, wait cnt2[b]==16, then
//    R9's verbatim bit-decode MFMA+LIF3+count loop -> atomicAdd.
__global__ __launch_bounds__(256, 4) void snn_fused(
    const float* __restrict__ x, const float* __restrict__ cw,
    const float* __restrict__ W1, const float* __restrict__ W2,
    unsigned char* __restrict__ s1, unsigned int* __restrict__ s2w,
    unsigned* __restrict__ bar, float* __restrict__ out) {
  const int bx  = blockIdx.x;
  const int tid = threadIdx.x;
  unsigned* cnt1 = bar;              // cnt1[b] at bar + b*16 (64 B lines)
  unsigned* cnt2 = bar + 1024;       // cnt2[b] at bar + 4096B + b*64B

  // ================= A: conv+LIF1 -> s1, out-zero =================
  {
    __shared__ float xs[200];
    const int b  = bx & 63;
    const int t0 = (bx >> 6) * 128;
    const float* xb = x + b * 2048;
    if (tid < 128) {
      for (int i = tid; i < 200; i += 128) {
        int l = t0 - 67 + i;
        xs[i] = (l >= 0 && l < 2048) ? xb[l] : 0.0f;
      }
    } else if (bx < 64 && tid < 128 + NCLS) {
      out[bx * NCLS + (tid - 128)] = 0.0f;   // re-poisoned 0xAA each call
    }
    __syncthreads();

    if (tid < 128) {
      const int c  = tid;
      const int ts = t0 - 64;
      float w[7];
#pragma unroll
      for (int k = 0; k < 7; ++k) w[k] = cw[c * 7 + k];
      float xw[7];
#pragma unroll
      for (int k = 0; k < 7; ++k) xw[k] = xs[k];
      float v = 0.0f;
#pragma unroll 7
      for (int i = 0; i < 192; ++i) {          // t = ts + i
        float u = fmaf(w[0], xw[0],
                  fmaf(w[1], xw[1],
                  fmaf(w[2], xw[2],
                  fmaf(w[3], xw[3],
                  fmaf(w[4], xw[4],
                  fmaf(w[5], xw[5], w[6] * xw[6]))))));
        v = fmaf(v, 0.5f, u);      // v*0.5 exact -> fmaf == ref mul-then-add
        bool sp = (v >= 1.0f);
        if (i >= 64) {
          int t = ts + i;
          s1[((size_t)t * BB + b) * CC + c] = (unsigned char)(sp ? 1 : 0);
        }
        if (sp) v = 0.0f;
#pragma unroll
        for (int k = 0; k < 6; ++k) xw[k] = xw[k + 1];
        xw[6] = xs[i + 7];
      }
    }
    release_count(cnt1 + (size_t)(bx & 63) * 16);
  }

  // ================= B: MFMA-i8 (s1 @ W1^T) + LIF2 -> s2 bits =================
  {
    const int lane = tid & 63;
    const int wv   = tid >> 6;
    const int hg   = bx >> 9;         // 0..1
    const int b    = (bx >> 3) & 63;  // 0..63
    const int chunk= bx & 7;          // 0..7
    const int t0   = chunk * 256;
    const int nwarm= (chunk == 0) ? 0 : 4;
    const int ts   = t0 - nwarm * 16;
    const int l15  = lane & 15;
    const int lg   = lane >> 4;
    const int nn   = lg >> 1;
    const int hb   = hg * 128 + wv * 32;

    // B fragments digitized in-register (identical bytes to the old dp loads)
    v4i Bf[2][4][2];
#pragma unroll
    for (int n = 0; n < 2; ++n)
#pragma unroll
      for (int kc = 0; kc < 2; ++kc) {
        v4i t4[4];
        digitize16(W1 + (size_t)(hb + n * 16 + l15) * CC + kc * 64 + lg * 16, t4);
#pragma unroll
        for (int d = 0; d < 4; ++d) Bf[n][d][kc] = t4[d];
      }

    acquire_count(cnt1 + (size_t)b * 16, 16);  // s1[.][b] ready

    const unsigned char* ap =
        s1 + ((size_t)(ts + l15) * BB + b) * CC + lg * 16;
    v4i Af0 = *(const v4i*)(ap);
    v4i Af1 = *(const v4i*)(ap + 64);
    ap += 16 * BB * CC;

    const int a4 = l15 * 4;
    float v = 0.0f;

    const int nsub = nwarm + 16;
    for (int s = 0; s < nsub; ++s) {
      const int tb = ts + s * 16;

      v4i Pf0 = *(const v4i*)(ap);     // final overrun lands in s2w region
      v4i Pf1 = *(const v4i*)(ap + 64);
      ap += 16 * BB * CC;

      float u0[4], u1[4];
#pragma unroll
      for (int n = 0; n < 2; ++n) {
        v4i a0 = {0, 0, 0, 0}, a1 = {0, 0, 0, 0}, a2 = {0, 0, 0, 0}, a3 = {0, 0, 0, 0};
        a0 = __builtin_amdgcn_mfma_i32_16x16x64_i8(Af0, Bf[n][0][0], a0, 0, 0, 0);
        a1 = __builtin_amdgcn_mfma_i32_16x16x64_i8(Af0, Bf[n][1][0], a1, 0, 0, 0);
        a2 = __builtin_amdgcn_mfma_i32_16x16x64_i8(Af0, Bf[n][2][0], a2, 0, 0, 0);
        a3 = __builtin_amdgcn_mfma_i32_16x16x64_i8(Af0, Bf[n][3][0], a3, 0, 0, 0);
        a0 = __builtin_amdgcn_mfma_i32_16x16x64_i8(Af1, Bf[n][0][1], a0, 0, 0, 0);
        a1 = __builtin_amdgcn_mfma_i32_16x16x64_i8(Af1, Bf[n][1][1], a1, 0, 0, 0);
        a2 = __builtin_amdgcn_mfma_i32_16x16x64_i8(Af1, Bf[n][2][1], a2, 0, 0, 0);
        a3 = __builtin_amdgcn_mfma_i32_16x16x64_i8(Af1, Bf[n][3][1], a3, 0, 0, 0);
#pragma unroll
        for (int r = 0; r < 4; ++r) {
          int hi = a3[r] * 256 + a2[r];           // exact, |.| < 2^24
          int lo = a1[r] * 256 + a0[r];
          float u = fmaf((float)hi, 0x1p-15f, (float)lo * 0x1p-31f);
          if (n == 0) u0[r] = u; else u1[r] = u;
        }
      }

      float ua[16];
#pragma unroll
      for (int q = 0; q < 4; ++q) {
        const int addr = a4 + q * 64;
#pragma unroll
        for (int r = 0; r < 4; ++r) {
          int g0 = __builtin_amdgcn_ds_bpermute(addr, __float_as_int(u0[r]));
          int g1 = __builtin_amdgcn_ds_bpermute(addr, __float_as_int(u1[r]));
          ua[q * 4 + r] = __int_as_float(nn ? g1 : g0);
        }
      }

      unsigned sel = 0;
#pragma unroll
      for (int j = 0; j < 16; ++j) {
        v = fmaf(v, 0.5f, ua[j]);
        bool sp = (v >= 1.0f);
        if (sp) v = 0.0f;
        unsigned long long Bm = __ballot(sp);
        if (l15 == j)
          sel = (unsigned)(Bm & 0xFFFFull) |
                ((unsigned)((Bm >> 32) & 0xFFFFull) << 16);
      }

      if (s >= nwarm && lg == 0)
        s2w[((size_t)(tb + l15) * BB + b) * 8 + hg * 4 + wv] = sel;

      Af0 = Pf0; Af1 = Pf1;
    }

    release_count(cnt2 + (size_t)b * 16);
  }

  // ================= C: MFMA-i8 (s2bits @ W2^T) + LIF3 + count =================
  {
    const int lane = tid & 63;
    const int wv   = tid >> 6;
    const int l15  = lane & 15;
    const int lg   = lane >> 4;
    const int b    = bx & 63;
    const int cg   = ((bx >> 6) << 2) | wv;   // 0..63, 32-t chunk per wave
    const int t0   = cg * 32;
    const int nwarm= (cg == 0) ? 0 : 4;
    const int ts   = t0 - nwarm * 16;

    v4i Bf[4][4];                    // [digit][kc]; col = l15 -> nc (pad rows 0)
#pragma unroll
    for (int kc = 0; kc < 4; ++kc) {
      float wl[16];
#pragma unroll
      for (int j = 0; j < 16; ++j)
        wl[j] = (l15 < NCLS) ? W2[l15 * HH + kc * 64 + lg * 16 + j] : 0.0f;
      v4i t4[4];
      digitize16(wl, t4);
#pragma unroll
      for (int d = 0; d < 4; ++d) Bf[d][kc] = t4[d];
    }

    acquire_count(cnt2 + (size_t)b * 16, 16);  // s2w[.][b] ready

    const uint4* rp = (const uint4*)s2w + ((size_t)(ts + l15) * BB + b) * 2;
    uint4 r0 = rp[0], r1 = rp[1];
    rp += 16 * BB * 2;

    const int a4 = l15 * 4;
    const int hw = (lg & 1) * 16;
    float v = 0.0f, cnt = 0.0f;

    const int nsub = nwarm + 2;
    for (int s = 0; s < nsub; ++s) {
      uint4 p0 = rp[0], p1 = rp[1];   // overrun past s2w lands in ws slack
      rp += 16 * BB * 2;

      unsigned rowd[8] = {r0.x, r0.y, r0.z, r0.w, r1.x, r1.y, r1.z, r1.w};

      v4i a0 = {0, 0, 0, 0}, a1 = {0, 0, 0, 0}, a2 = {0, 0, 0, 0}, a3 = {0, 0, 0, 0};
#pragma unroll
      for (int kc = 0; kc < 4; ++kc) {
        unsigned h16 = (rowd[kc * 2 + (lg >> 1)] >> hw) & 0xFFFFu;
        v4i Af;
        Af[0] = (int)(((h16 & 0xFu) * 0x00204081u) & 0x01010101u);
        Af[1] = (int)((((h16 >> 4) & 0xFu) * 0x00204081u) & 0x01010101u);
        Af[2] = (int)((((h16 >> 8) & 0xFu) * 0x00204081u) & 0x01010101u);
        Af[3] = (int)((((h16 >> 12) & 0xFu) * 0x00204081u) & 0x01010101u);
        a0 = __builtin_amdgcn_mfma_i32_16x16x64_i8(Af, Bf[0][kc], a0, 0, 0, 0);
        a1 = __builtin_amdgcn_mfma_i32_16x16x64_i8(Af, Bf[1][kc], a1, 0, 0, 0);
        a2 = __builtin_amdgcn_mfma_i32_16x16x64_i8(Af, Bf[2][kc], a2, 0, 0, 0);
        a3 = __builtin_amdgcn_mfma_i32_16x16x64_i8(Af, Bf[3][kc], a3, 0, 0, 0);
      }

      float u[4];
#pragma unroll
      for (int r = 0; r < 4; ++r) {
        int hi = a3[r] * 256 + a2[r];
        int lo = a1[r] * 256 + a0[r];
        u[r] = fmaf((float)hi, 0x1p-15f, (float)lo * 0x1p-31f);
      }

      float ua[16];
#pragma unroll
      for (int q = 0; q < 4; ++q) {
        const int addr = a4 + q * 64;
#pragma unroll
        for (int r = 0; r < 4; ++r)
          ua[q * 4 + r] = __int_as_float(
              __builtin_amdgcn_ds_bpermute(addr, __float_as_int(u[r])));
      }

      float inc = (s >= nwarm) ? 1.0f : 0.0f;
#pragma unroll
      for (int j = 0; j < 16; ++j) {
        v = fmaf(v, 0.5f, ua[j]);
        bool sp = (v >= 1.0f);
        if (sp) { v = 0.0f; cnt += inc; }
      }

      r0 = p0; r1 = p1;
    }

    if (lane < NCLS)
      atomicAdd(&out[b * NCLS + lane], cnt * (1.0f / 2048.0f));  // exact dyadic
  }
}

extern "C" void kernel_launch(void* const* d_in, const int* in_sizes, int n_in,
                              void* d_out, int out_size, void* d_ws, size_t ws_size,
                              hipStream_t stream) {
  const float* x  = (const float*)d_in[0];   // [64,2048]
  const float* cw = (const float*)d_in[1];   // [128,1,7]
  const float* W1 = (const float*)d_in[2];   // [256,128]
  const float* W2 = (const float*)d_in[3];   // [10,256]
  float* out = (float*)d_out;                // [64,10]

  char* ws = (char*)d_ws;
  unsigned char* s1  = (unsigned char*)(ws + S1_OFF);
  unsigned int*  s2w = (unsigned int*)(ws + S2W_OFF);
  unsigned*      bar = (unsigned*)(ws + BAR_OFF);

  hipMemsetAsync(bar, 0, 8192, stream);   // zero cnt1[64] + cnt2[64]
  snn_fused<<<dim3(1024), 256, 0, stream>>>(x, cw, W1, W2, s1, s2w, bar, out);
  (void)in_sizes; (void)n_in; (void)out_size; (void)ws_size;
}